// Round 1
// baseline (2533.102 us; speedup 1.0000x reference)
//
#include <hip/hip_runtime.h>

#define U_N 100000
#define I_N 50000
#define D_DIM 64
#define E_N 6400000
#define B_N 16384
#define N_N 150000
#define LAYERS 3

// ---------- init: emb0 = concat(user_emb, item_emb) ----------
__global__ __launch_bounds__(256) void init_emb(const float4* __restrict__ ue,
                                                const float4* __restrict__ ie,
                                                float4* __restrict__ emb) {
    const int n4 = N_N * D_DIM / 4;
    const int u4 = U_N * D_DIM / 4;
    for (int i = blockIdx.x * blockDim.x + threadIdx.x; i < n4;
         i += gridDim.x * blockDim.x) {
        emb[i] = (i < u4) ? ue[i] : ie[i - u4];
    }
}

// ---------- CSR build ----------
__global__ __launch_bounds__(256) void hist_kernel(const int* __restrict__ dst,
                                                   int* __restrict__ counts) {
    for (int e = blockIdx.x * blockDim.x + threadIdx.x; e < E_N;
         e += gridDim.x * blockDim.x) {
        atomicAdd(&counts[dst[e]], 1);
    }
}

// single-block exclusive scan, 1024 threads x 16 elems/thread per chunk
#define SCAN_T 1024
#define SCAN_PT 16
__global__ __launch_bounds__(SCAN_T) void scan_excl(const int* __restrict__ in,
                                                    int* __restrict__ out, int n) {
    __shared__ int lds[SCAN_T];
    int carry = 0;
    for (int base = 0; base < n; base += SCAN_T * SCAN_PT) {
        int v[SCAN_PT];
        int idx0 = base + threadIdx.x * SCAN_PT;
        int local = 0;
#pragma unroll
        for (int k = 0; k < SCAN_PT; ++k) {
            int i = idx0 + k;
            int x = (i < n) ? in[i] : 0;
            v[k] = local;      // exclusive within thread
            local += x;
        }
        lds[threadIdx.x] = local;
        __syncthreads();
        for (int off = 1; off < SCAN_T; off <<= 1) {
            int t = (threadIdx.x >= (unsigned)off) ? lds[threadIdx.x - off] : 0;
            __syncthreads();
            lds[threadIdx.x] += t;
            __syncthreads();
        }
        int texcl = lds[threadIdx.x] - local;   // exclusive across threads
        int chunk_total = lds[SCAN_T - 1];
        __syncthreads();
#pragma unroll
        for (int k = 0; k < SCAN_PT; ++k) {
            int i = idx0 + k;
            if (i < n) out[i] = carry + texcl + v[k];
        }
        carry += chunk_total;   // uniform across threads
    }
    if (threadIdx.x == 0) out[n] = carry;
}

__global__ __launch_bounds__(256) void copy_int(const int* __restrict__ in,
                                                int* __restrict__ out, int n) {
    for (int i = blockIdx.x * blockDim.x + threadIdx.x; i < n;
         i += gridDim.x * blockDim.x)
        out[i] = in[i];
}

__global__ __launch_bounds__(256) void scatter_kernel(const int* __restrict__ src,
                                                      const int* __restrict__ dst,
                                                      const float* __restrict__ vals,
                                                      int* __restrict__ cursor,
                                                      int* __restrict__ csr_src,
                                                      float* __restrict__ csr_val) {
    for (int e = blockIdx.x * blockDim.x + threadIdx.x; e < E_N;
         e += gridDim.x * blockDim.x) {
        int d = dst[e];
        int pos = atomicAdd(&cursor[d], 1);
        csr_src[pos] = src[e];
        csr_val[pos] = vals[e];
    }
}

// ---------- SpMM pull: one 64-lane wave per dst row, lane = column ----------
__global__ __launch_bounds__(256) void spmm_kernel(const float* __restrict__ ecur,
                                                   float* __restrict__ enext,
                                                   const int* __restrict__ row_ptr,
                                                   const int* __restrict__ csr_src,
                                                   const float* __restrict__ csr_val) {
    int row = blockIdx.x * (blockDim.x >> 6) + (threadIdx.x >> 6);
    int lane = threadIdx.x & 63;
    if (row >= N_N) return;
    int beg = row_ptr[row];
    int end = row_ptr[row + 1];
    float acc = 0.0f;
    for (int e = beg; e < end; ++e) {
        int s = csr_src[e];          // same addr across lanes -> broadcast fetch
        float v = csr_val[e];
        acc += v * ecur[(size_t)s * D_DIM + lane];   // 256B coalesced gather
    }
    enext[(size_t)row * D_DIM + lane] = acc;
}

// ---------- accumulate sampled rows into su/si ----------
__global__ __launch_bounds__(256) void accum_batch(const float* __restrict__ emb,
                                                   const int* __restrict__ users,
                                                   const int* __restrict__ items,
                                                   float* __restrict__ su,
                                                   float* __restrict__ si) {
    int r = blockIdx.x * (blockDim.x >> 6) + (threadIdx.x >> 6);
    int lane = threadIdx.x & 63;
    if (r >= 2 * B_N) return;
    if (r < B_N) {
        int node = users[r];
        su[(size_t)r * D_DIM + lane] += emb[(size_t)node * D_DIM + lane];
    } else {
        int b = r - B_N;
        int node = U_N + items[b];
        si[(size_t)b * D_DIM + lane] += emb[(size_t)node * D_DIM + lane];
    }
}

// ---------- gamma = su.si/16 + 64*(ub+ib) ----------
__global__ __launch_bounds__(256) void gamma_kernel(const float* __restrict__ su,
                                                    const float* __restrict__ si,
                                                    const float* __restrict__ ub,
                                                    const float* __restrict__ ib,
                                                    const int* __restrict__ users,
                                                    const int* __restrict__ items,
                                                    float* __restrict__ out) {
    int b = blockIdx.x * (blockDim.x >> 6) + (threadIdx.x >> 6);
    int lane = threadIdx.x & 63;
    if (b >= B_N) return;
    float p = su[(size_t)b * D_DIM + lane] * si[(size_t)b * D_DIM + lane];
#pragma unroll
    for (int off = 32; off > 0; off >>= 1) p += __shfl_xor(p, off, 64);
    if (lane == 0) {
        float bias = ub[users[b]] + ib[items[b]];
        out[b] = p * (1.0f / 16.0f) + 64.0f * bias;
    }
}

extern "C" void kernel_launch(void* const* d_in, const int* in_sizes, int n_in,
                              void* d_out, int out_size, void* d_ws, size_t ws_size,
                              hipStream_t stream) {
    const float* user_emb  = (const float*)d_in[0];
    const float* item_emb  = (const float*)d_in[1];
    const float* user_bias = (const float*)d_in[2];
    const float* item_bias = (const float*)d_in[3];
    const float* vals      = (const float*)d_in[4];
    const int*   src       = (const int*)d_in[5];
    const int*   dst       = (const int*)d_in[6];
    const int*   users     = (const int*)d_in[7];
    const int*   items     = (const int*)d_in[8];
    float* out = (float*)d_out;

    char* ws = (char*)d_ws;
    size_t off = 0;
    auto alloc = [&](size_t bytes) -> void* {
        void* p = ws + off;
        off += (bytes + 255) & ~(size_t)255;
        return p;
    };
    float* emb0    = (float*)alloc(sizeof(float) * (size_t)N_N * D_DIM);
    float* emb1    = (float*)alloc(sizeof(float) * (size_t)N_N * D_DIM);
    float* su      = (float*)alloc(sizeof(float) * (size_t)B_N * D_DIM);
    float* si      = (float*)alloc(sizeof(float) * (size_t)B_N * D_DIM);
    int*   row_ptr = (int*)alloc(sizeof(int) * (N_N + 1));
    int*   cursor  = (int*)alloc(sizeof(int) * (N_N + 1));
    int*   csr_src = (int*)alloc(sizeof(int) * (size_t)E_N);
    float* csr_val = (float*)alloc(sizeof(float) * (size_t)E_N);

    // zero accumulators & histogram (su,si are adjacent 4MB blocks)
    hipMemsetAsync(su, 0, sizeof(float) * (size_t)B_N * D_DIM * 2, stream);
    hipMemsetAsync(cursor, 0, sizeof(int) * (N_N + 1), stream);

    init_emb<<<2048, 256, 0, stream>>>((const float4*)user_emb,
                                       (const float4*)item_emb, (float4*)emb0);
    hist_kernel<<<2048, 256, 0, stream>>>(dst, cursor);
    scan_excl<<<1, SCAN_T, 0, stream>>>(cursor, row_ptr, N_N);
    copy_int<<<1024, 256, 0, stream>>>(row_ptr, cursor, N_N);
    scatter_kernel<<<2048, 256, 0, stream>>>(src, dst, vals, cursor, csr_src, csr_val);

    // layer 0 contribution
    accum_batch<<<(2 * B_N) / 4, 256, 0, stream>>>(emb0, users, items, su, si);

    float* cur = emb0;
    float* nxt = emb1;
    for (int l = 0; l < LAYERS; ++l) {
        spmm_kernel<<<(N_N + 3) / 4, 256, 0, stream>>>(cur, nxt, row_ptr, csr_src, csr_val);
        accum_batch<<<(2 * B_N) / 4, 256, 0, stream>>>(nxt, users, items, su, si);
        float* t = cur; cur = nxt; nxt = t;
    }

    gamma_kernel<<<B_N / 4, 256, 0, stream>>>(su, si, user_bias, item_bias,
                                              users, items, out);
}